// Round 12
// baseline (443.745 us; speedup 1.0000x reference)
//
#include <hip/hip_runtime.h>
#include <hip/hip_bf16.h>

// 3-layer tanh RNN. B=32, T=64, D_IN=10000, H=200, N_CLASSES=2.
//
// R19:
//  * MFMA REC, AGPR-FORCED: R18 proved the MFMA recurrence math (absmax
//    identical 7.6e-6) but the W-frag ARRAYS went to scratch (VGPR=88 vs
//    112 declared; 229KB/step reload = 3000cy = measured 1.27us/step).
//    Fix: 28 NAMED i32x4 W-frags used via inline-asm MFMA with "a"
//    constraints -- gfx950 MFMA reads B operands from AGPRs directly
//    (ISA §10), so the allocator must keep them AGPR-resident (unified
//    file: 8 waves/CU -> 256 regs/wave; ~112a + ~80v fits). h stays in
//    LDS hi/lo planes; per-step reads are 4-distinct-address broadcast
//    ds_read_b128 (cheap). Step model ~700cy vs scalar 1550.
//  * chain frame, 3 launches, pack_all/gemm_l0/gemm_job: R18-unchanged.
//  * split-bf16 3-term everywhere: ~fp32 accuracy at bf16 MFMA rate.

typedef __bf16  bf16x8 __attribute__((ext_vector_type(8)));
typedef __bf16  bf16x4 __attribute__((ext_vector_type(4)));
typedef float   f32x4  __attribute__((ext_vector_type(4)));
typedef int     i32x4  __attribute__((ext_vector_type(4)));

#define HDIM 200
#define BM 64
#define CHUNK_B 26624   // bytes per packed k-chunk: hi 13 tiles x 1KB, lo same
#define MFMA(a, b, c) __builtin_amdgcn_mfma_f32_16x16x32_bf16(a, b, c, 0, 0, 0)

__device__ __forceinline__ void glds16(const void* g, void* l) {
    __builtin_amdgcn_global_load_lds(
        (const __attribute__((address_space(1))) unsigned int*)g,
        (__attribute__((address_space(3))) unsigned int*)l, 16, 0, 0);
}

__device__ __forceinline__ float fast_tanh(float x) {
    float e = __expf(-2.f * fabsf(x));
    float r = (1.f - e) / (1.f + e);
    return copysignf(r, x);
}

// LDS-only barrier: waits LDS ops, NOT in-flight global stores (no vmcnt).
__device__ __forceinline__ void bar_lds() {
    asm volatile("s_waitcnt lgkmcnt(0)" ::: "memory");
    __builtin_amdgcn_s_barrier();
}

// ---- pack [HDIM x K] fp32 -> chunks in FRAGMENT ORDER (R14-proven).
// Packs 6 matrices: W_ih0/1/2 and W_hh0/1/2. ----
__global__ void pack_all(const float* __restrict__ Wi0,
                         const float* __restrict__ Wi1,
                         const float* __restrict__ Wi2,
                         const float* __restrict__ Wh0,
                         const float* __restrict__ Wh1,
                         const float* __restrict__ Wh2,
                         __bf16* __restrict__ Oi0,
                         __bf16* __restrict__ Oi1,
                         __bf16* __restrict__ Oi2,
                         __bf16* __restrict__ Oh0,
                         __bf16* __restrict__ Oh1,
                         __bf16* __restrict__ Oh2)
{
    const int T0 = 320 * 1664, TS = 7 * 1664;   // W_ih0; all others 7 chunks
    const int total = T0 + 5 * TS;
    for (int gt = blockIdx.x * blockDim.x + threadIdx.x; gt < total;
         gt += gridDim.x * blockDim.x) {
        const float* W; __bf16* out; int K, g;
        if (gt < T0)               { W = Wi0; out = Oi0; K = 10000; g = gt; }
        else {
            int r5 = gt - T0;
            int which = r5 / TS;   g = r5 - which * TS;  K = HDIM;
            switch (which) {
                case 0: W = Wi1; out = Oi1; break;
                case 1: W = Wi2; out = Oi2; break;
                case 2: W = Wh0; out = Oh0; break;
                case 3: W = Wh1; out = Oh1; break;
                default: W = Wh2; out = Oh2; break;
            }
        }

        const int kc = g / 1664;
        const int u  = g - kc * 1664;
        const int isLo = (u >= 832);
        const int u2 = isLo ? u - 832 : u;
        const int nt = u2 >> 6;              // n-tile 0..12
        const int l  = u2 & 63;              // lane slot
        const int r  = nt * 16 + (l & 15);   // 0..207
        const int k  = kc * 32 + (l >> 4) * 8;
        bf16x8 v;
        if (r < HDIM && k < K) {             // K % 8 == 0
            const float* p = W + (size_t)r * K + k;
            float4 a = *(const float4*)p, b = *(const float4*)(p + 4);
            float f[8] = {a.x, a.y, a.z, a.w, b.x, b.y, b.z, b.w};
#pragma unroll
            for (int i = 0; i < 8; ++i) {
                __bf16 h = (__bf16)f[i];
                v[i] = isLo ? (__bf16)(f[i] - (float)h) : h;
            }
        } else {
#pragma unroll
            for (int i = 0; i < 8; ++i) v[i] = (__bf16)0.f;
        }
        *(bf16x8*)&out[(size_t)g * 8] = v;
    }
}

// ---- one GEMM tile-job (R14-exact body). Ab: 2x4096 bf16, Bb: 2x13312. ----
__device__ __noinline__ void gemm_job(
    const float* __restrict__ A, int lda, int K,
    const __bf16* __restrict__ Bpack, float* __restrict__ C,
    int ksteps, int kc0, int m0,
    __bf16* Ab, __bf16* Bb, int tid)
{
    const int wv = tid >> 6, lane = tid & 63;
    const int r16 = lane & 15, kg = lane >> 4;
    const int mg = wv & 1, ng = wv >> 1;
    const int nt0 = ng ? 1 + ng * 3 : 0;        // 0,4,7,10
    const int ntw = ng ? 3 : 4;
    const int fb  = lane * 8;                   // lane's fragment offset (bf16)

    const int a_row = tid >> 3;          // 0..63
    const int a_q   = tid & 7;           // float4 column group
    const float* Arow = A + (size_t)(m0 + a_row) * lda + a_q * 4;
    const int a_off = (a_row >> 4) * 512 + ((a_row & 15) + 16 * (a_q >> 1)) * 8
                    + (a_q & 1) * 4;

    f32x4 acc[2][4];
#pragma unroll
    for (int mi = 0; mi < 2; ++mi)
#pragma unroll
        for (int j = 0; j < 4; ++j) acc[mi][j] = (f32x4)0.f;

    float av[4];
    auto loadA = [&](int ks) {
        const int kb = (kc0 + ks) * 32;
        if (kb + a_q * 4 < K) {          // 4-granular, K % 4 == 0
            float4 x0 = *(const float4*)(Arow + kb);
            av[0] = x0.x; av[1] = x0.y; av[2] = x0.z; av[3] = x0.w;
        } else {
#pragma unroll
            for (int i = 0; i < 4; ++i) av[i] = 0.f;
        }
    };
    auto issueB = [&](int ks, int buf) {
        const char* src = (const char*)Bpack + (size_t)(kc0 + ks) * CHUNK_B;
        char* dst = (char*)Bb + (size_t)buf * CHUNK_B;
#pragma unroll
        for (int r = 0; r < 3; ++r)
            glds16(src + (r * 512 + tid) * 16, dst + (r * 512 + tid) * 16);
        if (tid < 128)
            glds16(src + (1536 + tid) * 16, dst + (1536 + tid) * 16);
    };

    loadA(0);
    issueB(0, 0);

    for (int ks = 0; ks < ksteps; ++ks) {
        const int cur = ks & 1, nxt = cur ^ 1;
        bf16x4 th, tl;
#pragma unroll
        for (int i = 0; i < 4; ++i) {
            __bf16 h = (__bf16)av[i];
            th[i] = h; tl[i] = (__bf16)(av[i] - (float)h);
        }
        *(bf16x4*)&Ab[cur * 4096 + a_off]        = th;
        *(bf16x4*)&Ab[cur * 4096 + 2048 + a_off] = tl;
        __syncthreads();   // drains glds B(ks) + A writes (vmcnt+lgkm)
        if (ks + 1 < ksteps) { issueB(ks + 1, nxt); loadA(ks + 1); }

        const int ao0 = (mg * 2 + 0) * 512 + fb;
        const int ao1 = (mg * 2 + 1) * 512 + fb;
        bf16x8 ah0 = *(const bf16x8*)&Ab[cur * 4096 + ao0];
        bf16x8 al0 = *(const bf16x8*)&Ab[cur * 4096 + 2048 + ao0];
        bf16x8 ah1 = *(const bf16x8*)&Ab[cur * 4096 + ao1];
        bf16x8 al1 = *(const bf16x8*)&Ab[cur * 4096 + 2048 + ao1];
#pragma unroll
        for (int j = 0; j < 4; ++j) {
            if (j < ntw) {
                const int bo = (nt0 + j) * 512 + fb;
                bf16x8 bh = *(const bf16x8*)&Bb[cur * 13312 + bo];
                bf16x8 bl = *(const bf16x8*)&Bb[cur * 13312 + 6656 + bo];
                acc[0][j] = MFMA(al0, bh, acc[0][j]);
                acc[0][j] = MFMA(ah0, bl, acc[0][j]);
                acc[0][j] = MFMA(ah0, bh, acc[0][j]);
                acc[1][j] = MFMA(al1, bh, acc[1][j]);
                acc[1][j] = MFMA(ah1, bl, acc[1][j]);
                acc[1][j] = MFMA(ah1, bh, acc[1][j]);
            }
        }
    }

    // epilogue: C/D layout col=lane&15, row=(lane>>4)*4+reg
#pragma unroll
    for (int mi = 0; mi < 2; ++mi) {
        const int rb = m0 + mg * 32 + mi * 16 + kg * 4;
#pragma unroll
        for (int j = 0; j < 4; ++j) {
            if (j < ntw) {
                const int n = (nt0 + j) * 16 + r16;
                if (n < HDIM)
#pragma unroll
                    for (int r = 0; r < 4; ++r)
                        C[(size_t)(rb + r) * HDIM + n] = acc[mi][j][r];
            }
        }
    }
    __syncthreads();   // drains loads/stores; LDS safe for next phase
}

// ---- L0 GEMM wrapper: grid (32 m-blocks, 16 k-splits) ----
__global__ __launch_bounds__(512, 4)
void gemm_l0(const float* __restrict__ x, const __bf16* __restrict__ W0p,
             float* __restrict__ Ppart, int per_split)
{
    __shared__ alignas(16) char U[69632];
    gemm_job(x, 10000, 10000, W0p,
             Ppart + (size_t)blockIdx.y * per_split,
             20, blockIdx.y * 20, blockIdx.x * BM,
             (__bf16*)U, (__bf16*)(U + 16384), threadIdx.x);
}

// AGPR-forced MFMA: D,C = acc (VGPR); A = h-frag (VGPR); B = W-frag (AGPR).
#define MFMA_A(ACC, AF, BF) \
    asm("v_mfma_f32_16x16x32_bf16 %0, %1, %2, %0" \
        : "+v"(ACC) : "v"(AF), "a"(BF))

// ---- per-batch chain: [sum partials ->] rec0 -> gemm1 -> rec1 -> gemm2
//      -> rec2 -> fc. 32 blocks, 1 per batch. AGPR-MFMA recurrence. ----
__global__ __launch_bounds__(512, 1)
void rnn_chain(const float* __restrict__ Ppart, int nparts, int pstride,
               float* P, float* Hbuf,
               const __bf16* __restrict__ Wh0p, const float* __restrict__ bih0,
               const float* __restrict__ bhh0,
               const __bf16* __restrict__ Wh1p, const float* __restrict__ bih1,
               const float* __restrict__ bhh1,
               const __bf16* __restrict__ Wh2p, const float* __restrict__ bih2,
               const float* __restrict__ bhh2,
               const __bf16* __restrict__ W1p, const __bf16* __restrict__ W2p,
               const float* __restrict__ fcw, const float* __restrict__ fcb,
               float* __restrict__ outp)
{
    const int b   = blockIdx.x;
    const int tid = threadIdx.x;

    __shared__ alignas(16) char U[69632];     // union: gemm Ab+Bb | rec bufs
    __bf16* Ab   = (__bf16*)U;
    __bf16* Bb   = (__bf16*)(U + 16384);
    float*  preS = (float*)U;                 // 12800 f
    float*  bias = (float*)(U + 51200);       // 200 f
    float*  hF   = (float*)(U + 52000);       // 200 f (fp32 h for fc head)
    __bf16* hSh  = (__bf16*)(U + 52800);      // 224 bf16 (hi plane, padded)
    __bf16* hSl  = (__bf16*)(U + 53264);      // 224 bf16 (lo plane)

    const int wv = tid >> 6, lane = tid & 63;
    const int kg = lane >> 4;                 // A-frag k-subgroup
    const int ntA = wv;                       // n-tiles owned: wv and wv+8
    const int ntB = wv + 8;
    const bool hasB = (ntB < 13);

    // MFMA recurrence: h_{t+1} = tanh(pre_t + h_t @ Whh^T).
    // Row-broadcast A (all rows = h) -> every C row = result; lanes 0-15
    // reg0 extract. W-frags in 28 NAMED i32x4, AGPR-forced at each use.
    // Layout proven by R14 (gemm) + R18 (rec absmax match).
    auto recM = [&](const float* preG, int np, int pstr,
                    const __bf16* WhhP, const float* bih, const float* bhh,
                    float* Hout) {
        {   // stage pre slab, summing np k-split partials (coalesced)
            const float4* ps = (const float4*)(preG + (size_t)b * 64 * HDIM);
            float4* pd = (float4*)preS;
            const size_t pq = (size_t)pstr / 4;
            for (int i = tid; i < 3200; i += 512) {
                float4 s = ps[i];
                for (int r = 1; r < np; ++r) {
                    float4 v = ps[(size_t)r * pq + i];
                    s.x += v.x; s.y += v.y; s.z += v.z; s.w += v.w;
                }
                pd[i] = s;
            }
        }
        if (tid < HDIM) bias[tid] = bih[tid] + bhh[tid];
        if (tid < 224) { hSh[tid] = (__bf16)0.f; hSl[tid] = (__bf16)0.f; }

        // 28 named W-fragments (i32x4 bitcast of bf16x8), loaded once.
#define LDWF(KC) \
        i32x4 wAh##KC, wAl##KC, wBh##KC, wBl##KC; \
        { const __bf16* s0 = WhhP + (size_t)KC * 13312 \
                           + ((size_t)ntA * 64 + lane) * 8; \
          wAh##KC = *(const i32x4*)s0; \
          wAl##KC = *(const i32x4*)(s0 + 6656); \
          if (hasB) { \
            const __bf16* s1 = WhhP + (size_t)KC * 13312 \
                             + ((size_t)ntB * 64 + lane) * 8; \
            wBh##KC = *(const i32x4*)s1; \
            wBl##KC = *(const i32x4*)(s1 + 6656); \
          } else { wBh##KC = (i32x4)0; wBl##KC = (i32x4)0; } }
        LDWF(0) LDWF(1) LDWF(2) LDWF(3) LDWF(4) LDWF(5) LDWF(6)
#undef LDWF
        __syncthreads();

        for (int t = 0; t < 64; ++t) {
            f32x4 aA = (f32x4)0.f, aB = (f32x4)0.f;
#define REC_KC(KC) { \
            i32x4 hh = *(const i32x4*)&hSh[KC * 32 + kg * 8]; \
            i32x4 hl = *(const i32x4*)&hSl[KC * 32 + kg * 8]; \
            MFMA_A(aA, hl, wAh##KC); \
            MFMA_A(aA, hh, wAl##KC); \
            MFMA_A(aA, hh, wAh##KC); \
            if (hasB) { \
                MFMA_A(aB, hl, wBh##KC); \
                MFMA_A(aB, hh, wBl##KC); \
                MFMA_A(aB, hh, wBh##KC); \
            } }
            REC_KC(0) REC_KC(1) REC_KC(2) REC_KC(3)
            REC_KC(4) REC_KC(5) REC_KC(6)
#undef REC_KC
            bar_lds();   // all waves' h-frag reads done -> hS safe to rewrite
            if (lane < 16) {
                {   // ntA tile: n = ntA*16+lane, always < 128 < 200
                    const int n = ntA * 16 + lane;
                    float v = fast_tanh(aA[0] + preS[t * HDIM + n] + bias[n]);
                    __bf16 vh = (__bf16)v;
                    hSh[n] = vh; hSl[n] = (__bf16)(v - (float)vh);
                    hF[n] = v;
                    Hout[((size_t)b * 64 + t) * HDIM + n] = v;
                }
                const int n = ntB * 16 + lane;
                if (n < HDIM) {
                    float v = fast_tanh(aB[0] + preS[t * HDIM + n] + bias[n]);
                    __bf16 vh = (__bf16)v;
                    hSh[n] = vh; hSl[n] = (__bf16)(v - (float)vh);
                    hF[n] = v;
                    Hout[((size_t)b * 64 + t) * HDIM + n] = v;
                }
            }
            bar_lds();   // h(t+1) visible for next step's A-frag reads
        }
    };

    float* Hslab = Hbuf + (size_t)b * 64 * HDIM;
    float* Pslab = P + (size_t)b * 64 * HDIM;

    recM(Ppart, nparts, pstride, Wh0p, bih0, bhh0, Hbuf);
    __syncthreads();                          // drain Hout stores before gemm reads
    gemm_job(Hslab, HDIM, HDIM, W1p, Pslab, 7, 0, 0, Ab, Bb, tid);

    recM(P, 1, 0, Wh1p, bih1, bhh1, Hbuf);
    __syncthreads();
    gemm_job(Hslab, HDIM, HDIM, W2p, Pslab, 7, 0, 0, Ab, Bb, tid);

    recM(P, 1, 0, Wh2p, bih2, bhh2, Hbuf);

    // fc head: hF holds fp32 h_63 (last bar_lds made it visible)
    if (tid < 16) {
        const int cls = tid & 1, sl = tid >> 1;      // 8 slices of 25
        const float* fw = fcw + cls * HDIM + sl * 25;
        const float* hp = hF + sl * 25;
        float sacc = 0.f;
#pragma unroll
        for (int j = 0; j < 25; ++j) sacc += hp[j] * fw[j];
        sacc += __shfl_xor(sacc, 2);
        sacc += __shfl_xor(sacc, 4);
        sacc += __shfl_xor(sacc, 8);
        if (sl == 0) outp[b * 2 + cls] = sacc + fcb[cls];
    }
}

extern "C" void kernel_launch(void* const* d_in, const int* in_sizes, int n_in,
                              void* d_out, int out_size, void* d_ws, size_t ws_size,
                              hipStream_t stream) {
    const float* x     = (const float*)d_in[0];
    const float* W_ih0 = (const float*)d_in[1];
    const float* W_hh0 = (const float*)d_in[2];
    const float* b_ih0 = (const float*)d_in[3];
    const float* b_hh0 = (const float*)d_in[4];
    const float* W_ih1 = (const float*)d_in[5];
    const float* W_hh1 = (const float*)d_in[6];
    const float* b_ih1 = (const float*)d_in[7];
    const float* b_hh1 = (const float*)d_in[8];
    const float* W_ih2 = (const float*)d_in[9];
    const float* W_hh2 = (const float*)d_in[10];
    const float* b_ih2 = (const float*)d_in[11];
    const float* b_hh2 = (const float*)d_in[12];
    const float* fc_w  = (const float*)d_in[13];
    const float* fc_b  = (const float*)d_in[14];
    float* out = (float*)d_out;

    const size_t PE = (size_t)2048 * HDIM;          // 409600
    const size_t CH = (size_t)7 * 13312;            // small pack size (bf16)
    float* P     = (float*)d_ws;
    float* Hbuf  = P + PE;
    float* Ppart = Hbuf + PE;                       // 16 x 409600
    __bf16* W0p  = (__bf16*)(Ppart + 16 * PE);      // 320 chunks
    __bf16* W1p  = W0p + (size_t)320 * 13312;
    __bf16* W2p  = W1p + CH;
    __bf16* Wh0p = W2p + CH;
    __bf16* Wh1p = Wh0p + CH;
    __bf16* Wh2p = Wh1p + CH;
    // total ws: ~39 MB

    // ---- 3 launches total ----
    pack_all<<<1024, 256, 0, stream>>>(W_ih0, W_ih1, W_ih2,
                                       W_hh0, W_hh1, W_hh2,
                                       W0p, W1p, W2p, Wh0p, Wh1p, Wh2p);
    gemm_l0<<<dim3(32, 16), 512, 0, stream>>>(x, W0p, Ppart, (int)PE);
    rnn_chain<<<32, 512, 0, stream>>>(Ppart, 16, (int)PE, P, Hbuf,
                                      Wh0p, b_ih0, b_hh0,
                                      Wh1p, b_ih1, b_hh1,
                                      Wh2p, b_ih2, b_hh2,
                                      W1p, W2p, fc_w, fc_b, out);
}

// Round 14
// 391.771 us; speedup vs baseline: 1.1327x; 1.1327x over previous
//
#include <hip/hip_runtime.h>
#include <hip/hip_bf16.h>

// 3-layer tanh RNN. B=32, T=64, D_IN=10000, H=200, N_CLASSES=2.
//
// R21 == R20 resubmitted verbatim (R13 bench died with "MI355X container
// failed twice" -- broker/infra failure, no correctness signal; kernel
// audited for hangs: all threads reach both bar_lds barriers, clamped
// loads are in-bounds, no cooperative launch, no forbidden APIs).
//
// R20 notes:
//  * MFMA REC, INTRINSIC + NAMED FRAGS: R18 proved the MFMA rec math
//    (absmax 7.6e-6) but arrays sent W-frags to scratch; R19's raw-asm
//    attempt broke numerics (no compiler hazard model: absmax 2e-3) and
//    was slower (v->a copies). This version: standalone __global__ (own
//    regalloc), 28 individually-NAMED bf16x8 W-frags (no arrays, no
//    lambda), INTRINSIC MFMA (hazards handled), no divergent hasB (the
//    invalid ntB>=13 tile loads a clamped address; its result is already
//    write-gated by n<HDIM), accumulator chains split 21 -> 11+10.
//  * frame: R14's proven 9-launch structure (best measured, frag-order
//    pack); only rnn_rec -> rnn_recM swapped, pack extended to Whh0/1/2.
//  * gemm_pipe / reduce_parts / fc_head: R14/R13-exact.
//  * split-bf16 3-term everywhere: ~fp32 accuracy at bf16 MFMA rate.

typedef __bf16  bf16x8 __attribute__((ext_vector_type(8)));
typedef __bf16  bf16x4 __attribute__((ext_vector_type(4)));
typedef float   f32x4  __attribute__((ext_vector_type(4)));

#define HDIM 200
#define BM 64
#define CHUNK_B 26624   // bytes per packed k-chunk: hi 13 tiles x 1KB, lo same
#define MFMA(a, b, c) __builtin_amdgcn_mfma_f32_16x16x32_bf16(a, b, c, 0, 0, 0)

__device__ __forceinline__ void glds16(const void* g, void* l) {
    __builtin_amdgcn_global_load_lds(
        (const __attribute__((address_space(1))) unsigned int*)g,
        (__attribute__((address_space(3))) unsigned int*)l, 16, 0, 0);
}

__device__ __forceinline__ float fast_tanh(float x) {
    float e = __expf(-2.f * fabsf(x));
    float r = (1.f - e) / (1.f + e);
    return copysignf(r, x);
}

// LDS-only barrier: waits LDS ops, NOT in-flight global stores (no vmcnt).
__device__ __forceinline__ void bar_lds() {
    asm volatile("s_waitcnt lgkmcnt(0)" ::: "memory");
    __builtin_amdgcn_s_barrier();
}

// ---- pack [HDIM x K] fp32 -> chunks in FRAGMENT ORDER (R14-proven).
// Packs 6 matrices: W_ih0/1/2 and W_hh0/1/2. ----
__global__ void pack_all(const float* __restrict__ Wi0,
                         const float* __restrict__ Wi1,
                         const float* __restrict__ Wi2,
                         const float* __restrict__ Wh0,
                         const float* __restrict__ Wh1,
                         const float* __restrict__ Wh2,
                         __bf16* __restrict__ Oi0,
                         __bf16* __restrict__ Oi1,
                         __bf16* __restrict__ Oi2,
                         __bf16* __restrict__ Oh0,
                         __bf16* __restrict__ Oh1,
                         __bf16* __restrict__ Oh2)
{
    const int T0 = 320 * 1664, TS = 7 * 1664;   // W_ih0; all others 7 chunks
    const int total = T0 + 5 * TS;
    for (int gt = blockIdx.x * blockDim.x + threadIdx.x; gt < total;
         gt += gridDim.x * blockDim.x) {
        const float* W; __bf16* out; int K, g;
        if (gt < T0)               { W = Wi0; out = Oi0; K = 10000; g = gt; }
        else {
            int r5 = gt - T0;
            int which = r5 / TS;   g = r5 - which * TS;  K = HDIM;
            switch (which) {
                case 0: W = Wi1; out = Oi1; break;
                case 1: W = Wi2; out = Oi2; break;
                case 2: W = Wh0; out = Oh0; break;
                case 3: W = Wh1; out = Oh1; break;
                default: W = Wh2; out = Oh2; break;
            }
        }

        const int kc = g / 1664;
        const int u  = g - kc * 1664;
        const int isLo = (u >= 832);
        const int u2 = isLo ? u - 832 : u;
        const int nt = u2 >> 6;              // n-tile 0..12
        const int l  = u2 & 63;              // lane slot
        const int r  = nt * 16 + (l & 15);   // 0..207
        const int k  = kc * 32 + (l >> 4) * 8;
        bf16x8 v;
        if (r < HDIM && k < K) {             // K % 8 == 0
            const float* p = W + (size_t)r * K + k;
            float4 a = *(const float4*)p, b = *(const float4*)(p + 4);
            float f[8] = {a.x, a.y, a.z, a.w, b.x, b.y, b.z, b.w};
#pragma unroll
            for (int i = 0; i < 8; ++i) {
                __bf16 h = (__bf16)f[i];
                v[i] = isLo ? (__bf16)(f[i] - (float)h) : h;
            }
        } else {
#pragma unroll
            for (int i = 0; i < 8; ++i) v[i] = (__bf16)0.f;
        }
        *(bf16x8*)&out[(size_t)g * 8] = v;
    }
}

// ---- pipelined GEMM (R14-exact): frag-ordered LDS, one barrier/kstep ----
__global__ __launch_bounds__(512, 4)
void gemm_pipe(const float* __restrict__ A, int lda, int K,
               const __bf16* __restrict__ Bpack,
               float* __restrict__ Cbase, int per_split, int ksteps)
{
    __shared__ alignas(16) __bf16 Ab[2][4096];    // [hi 2048 | lo 2048] frag-order
    __shared__ alignas(16) __bf16 Bb[2][13312];   // [hi 6656 | lo 6656] frag-order

    const int tid = threadIdx.x;
    const int kc0 = blockIdx.y * ksteps;
    const int m0  = blockIdx.x * BM;
    float* __restrict__ C = Cbase + (size_t)blockIdx.y * per_split;

    const int wv = tid >> 6, lane = tid & 63;
    const int r16 = lane & 15, kg = lane >> 4;
    const int mg = wv & 1, ng = wv >> 1;
    const int nt0 = ng ? 1 + ng * 3 : 0;        // 0,4,7,10
    const int ntw = ng ? 3 : 4;
    const int fb  = lane * 8;                   // lane's fragment offset (bf16)

    const int a_row = tid >> 3;          // 0..63
    const int a_q   = tid & 7;           // float4 column group
    const float* Arow = A + (size_t)(m0 + a_row) * lda + a_q * 4;
    const int a_off = (a_row >> 4) * 512 + ((a_row & 15) + 16 * (a_q >> 1)) * 8
                    + (a_q & 1) * 4;

    f32x4 acc[2][4];
#pragma unroll
    for (int mi = 0; mi < 2; ++mi)
#pragma unroll
        for (int j = 0; j < 4; ++j) acc[mi][j] = (f32x4)0.f;

    float av[4];
    auto loadA = [&](int ks) {
        const int kb = (kc0 + ks) * 32;
        if (kb + a_q * 4 < K) {          // 4-granular, K % 4 == 0
            float4 x0 = *(const float4*)(Arow + kb);
            av[0] = x0.x; av[1] = x0.y; av[2] = x0.z; av[3] = x0.w;
        } else {
#pragma unroll
            for (int i = 0; i < 4; ++i) av[i] = 0.f;
        }
    };
    auto issueB = [&](int ks, int buf) {
        const char* src = (const char*)Bpack + (size_t)(kc0 + ks) * CHUNK_B;
        char* dst = (char*)&Bb[buf][0];
#pragma unroll
        for (int r = 0; r < 3; ++r)
            glds16(src + (r * 512 + tid) * 16, dst + (r * 512 + tid) * 16);
        if (tid < 128)
            glds16(src + (1536 + tid) * 16, dst + (1536 + tid) * 16);
    };

    loadA(0);
    issueB(0, 0);

    for (int ks = 0; ks < ksteps; ++ks) {
        const int cur = ks & 1, nxt = cur ^ 1;
        bf16x4 th, tl;
#pragma unroll
        for (int i = 0; i < 4; ++i) {
            __bf16 h = (__bf16)av[i];
            th[i] = h; tl[i] = (__bf16)(av[i] - (float)h);
        }
        *(bf16x4*)&Ab[cur][a_off]        = th;
        *(bf16x4*)&Ab[cur][2048 + a_off] = tl;
        __syncthreads();   // drains glds B(ks)->Bb[cur] + A writes (vmcnt+lgkm)
        if (ks + 1 < ksteps) { issueB(ks + 1, nxt); loadA(ks + 1); }

        const int ao0 = (mg * 2 + 0) * 512 + fb;
        const int ao1 = (mg * 2 + 1) * 512 + fb;
        bf16x8 ah0 = *(const bf16x8*)&Ab[cur][ao0];
        bf16x8 al0 = *(const bf16x8*)&Ab[cur][2048 + ao0];
        bf16x8 ah1 = *(const bf16x8*)&Ab[cur][ao1];
        bf16x8 al1 = *(const bf16x8*)&Ab[cur][2048 + ao1];
#pragma unroll
        for (int j = 0; j < 4; ++j) {
            if (j < ntw) {
                const int bo = (nt0 + j) * 512 + fb;
                bf16x8 bh = *(const bf16x8*)&Bb[cur][bo];
                bf16x8 bl = *(const bf16x8*)&Bb[cur][6656 + bo];
                acc[0][j] = MFMA(al0, bh, acc[0][j]);
                acc[0][j] = MFMA(ah0, bl, acc[0][j]);
                acc[0][j] = MFMA(ah0, bh, acc[0][j]);
                acc[1][j] = MFMA(al1, bh, acc[1][j]);
                acc[1][j] = MFMA(ah1, bl, acc[1][j]);
                acc[1][j] = MFMA(ah1, bh, acc[1][j]);
            }
        }
    }

    // epilogue: C/D layout col=lane&15, row=(lane>>4)*4+reg; plain stores
#pragma unroll
    for (int mi = 0; mi < 2; ++mi) {
        const int rb = m0 + mg * 32 + mi * 16 + kg * 4;
#pragma unroll
        for (int j = 0; j < 4; ++j) {
            if (j < ntw) {
                const int n = (nt0 + j) * 16 + r16;
                if (n < HDIM)
#pragma unroll
                    for (int r = 0; r < 4; ++r)
                        C[(size_t)(rb + r) * HDIM + n] = acc[mi][j][r];
            }
        }
    }
}

// ---- sum 16 k-split partials ----
__global__ void reduce_parts(const float* __restrict__ Pp, float* __restrict__ P)
{
    const int i = blockIdx.x * blockDim.x + threadIdx.x;   // float4 index
    if (i < 102400) {
        float4 s = ((const float4*)Pp)[i];
#pragma unroll
        for (int r = 1; r < 16; ++r) {
            float4 v = ((const float4*)Pp)[(size_t)r * 102400 + i];
            s.x += v.x; s.y += v.y; s.z += v.z; s.w += v.w;
        }
        ((float4*)P)[i] = s;
    }
}

// ---- MFMA recurrence: 1 block/batch, 8 waves. h_{t+1}=tanh(pre+h@Whh^T).
// Row-broadcast A (all 16 rows = h) -> every C row = result; lanes 0-15,
// reg 0 extract. 28 NAMED bf16x8 W-frags (intrinsic MFMA; no arrays).
// Wave wv owns n-tiles wv and wv+8; tiles >=13 load a clamped address and
// their result is discarded by the n<HDIM write gate. ----
__global__ __launch_bounds__(512, 1)
void rnn_recM(const float* __restrict__ pre,   // [32][64][200]
              const __bf16* __restrict__ WhhP, // 7 chunks frag-order
              const float* __restrict__ bih,
              const float* __restrict__ bhh,
              float* __restrict__ Hout)        // [32][64][200]
{
    const int b   = blockIdx.x;
    const int tid = threadIdx.x;

    __shared__ float preS[64 * HDIM];          // 51.2 KB
    __shared__ float bias[HDIM];
    __shared__ __bf16 hSh[224];                // h hi plane (padded)
    __shared__ __bf16 hSl[224];                // h lo plane

    {   // stage pre slab (coalesced)
        const float4* ps = (const float4*)(pre + (size_t)b * 64 * HDIM);
        float4* pd = (float4*)preS;
        for (int i = tid; i < 3200; i += 512) pd[i] = ps[i];
    }
    if (tid < HDIM) bias[tid] = bih[tid] + bhh[tid];
    if (tid < 224) { hSh[tid] = (__bf16)0.f; hSl[tid] = (__bf16)0.f; }

    const int wv = tid >> 6, lane = tid & 63, kg = lane >> 4;
    const int ntA = wv;                        // 0..7  (always valid)
    const int ntB = wv + 8;                    // 8..15 (13..15 invalid)
    const int ntBc = ntB < 13 ? ntB : 12;      // clamped load address

    const __bf16* bA = WhhP + ((size_t)ntA  * 64 + lane) * 8;
    const __bf16* bB = WhhP + ((size_t)ntBc * 64 + lane) * 8;
#define LW(KC) \
    const bf16x8 wAh##KC = *(const bf16x8*)(bA + KC * 13312); \
    const bf16x8 wAl##KC = *(const bf16x8*)(bA + KC * 13312 + 6656); \
    const bf16x8 wBh##KC = *(const bf16x8*)(bB + KC * 13312); \
    const bf16x8 wBl##KC = *(const bf16x8*)(bB + KC * 13312 + 6656);
    LW(0) LW(1) LW(2) LW(3) LW(4) LW(5) LW(6)
#undef LW
    __syncthreads();

    for (int t = 0; t < 64; ++t) {
        f32x4 aA0 = (f32x4)0.f, aA1 = (f32x4)0.f;   // split chains 11+10
        f32x4 aB0 = (f32x4)0.f, aB1 = (f32x4)0.f;
#define RK(KC, SA, SB) { \
        const bf16x8 hh = *(const bf16x8*)&hSh[KC * 32 + kg * 8]; \
        const bf16x8 hl = *(const bf16x8*)&hSl[KC * 32 + kg * 8]; \
        SA = MFMA(hl, wAh##KC, SA); SA = MFMA(hh, wAl##KC, SA); \
        SA = MFMA(hh, wAh##KC, SA); \
        SB = MFMA(hl, wBh##KC, SB); SB = MFMA(hh, wBl##KC, SB); \
        SB = MFMA(hh, wBh##KC, SB); }
        RK(0, aA0, aB0) RK(1, aA1, aB1) RK(2, aA0, aB0) RK(3, aA1, aB1)
        RK(4, aA0, aB0) RK(5, aA1, aB1) RK(6, aA0, aB0)
#undef RK
        const float rA = aA0[0] + aA1[0];
        const float rB = aB0[0] + aB1[0];
        bar_lds();   // all waves' h-frag reads done -> hS safe to rewrite
        if (lane < 16) {
            const int nA = ntA * 16 + lane;        // < 128 < HDIM always
            float v = fast_tanh(rA + preS[t * HDIM + nA] + bias[nA]);
            __bf16 vh = (__bf16)v;
            hSh[nA] = vh; hSl[nA] = (__bf16)(v - (float)vh);
            Hout[((size_t)b * 64 + t) * HDIM + nA] = v;
            const int nB = ntB * 16 + lane;
            if (nB < HDIM) {
                float v2 = fast_tanh(rB + preS[t * HDIM + nB] + bias[nB]);
                __bf16 vh2 = (__bf16)v2;
                hSh[nB] = vh2; hSl[nB] = (__bf16)(v2 - (float)vh2);
                Hout[((size_t)b * 64 + t) * HDIM + nB] = v2;
            }
        }
        bar_lds();   // h(t+1) visible for next step's reads
    }
}

// ---- trivially-correct FC head ----
__global__ void fc_head(const float* __restrict__ Hlast_base,
                        const float* __restrict__ fcw,
                        const float* __restrict__ fcb,
                        float* __restrict__ out)
{
    const int i = threadIdx.x;
    if (i >= 64) return;
    const int b = i >> 1, cls = i & 1;
    const float* hp = Hlast_base + ((size_t)b * 64 + 63) * HDIM;
    const float* fw = fcw + cls * HDIM;
    float s = fcb[cls];
    for (int j = 0; j < HDIM; ++j) s += hp[j] * fw[j];
    out[b * 2 + cls] = s;
}

extern "C" void kernel_launch(void* const* d_in, const int* in_sizes, int n_in,
                              void* d_out, int out_size, void* d_ws, size_t ws_size,
                              hipStream_t stream) {
    const float* x     = (const float*)d_in[0];
    const float* W_ih0 = (const float*)d_in[1];
    const float* W_hh0 = (const float*)d_in[2];
    const float* b_ih0 = (const float*)d_in[3];
    const float* b_hh0 = (const float*)d_in[4];
    const float* W_ih1 = (const float*)d_in[5];
    const float* W_hh1 = (const float*)d_in[6];
    const float* b_ih1 = (const float*)d_in[7];
    const float* b_hh1 = (const float*)d_in[8];
    const float* W_ih2 = (const float*)d_in[9];
    const float* W_hh2 = (const float*)d_in[10];
    const float* b_ih2 = (const float*)d_in[11];
    const float* b_hh2 = (const float*)d_in[12];
    const float* fc_w  = (const float*)d_in[13];
    const float* fc_b  = (const float*)d_in[14];
    float* out = (float*)d_out;

    const size_t PE = (size_t)2048 * HDIM;          // 409600
    const size_t CH = (size_t)7 * 13312;            // small pack size (bf16)
    float* P     = (float*)d_ws;
    float* Hbuf  = P + PE;
    float* Hbuf2 = Hbuf + PE;
    float* Ppart = Hbuf2 + PE;                      // 16 x 409600
    __bf16* W0p  = (__bf16*)(Ppart + 16 * PE);      // 320 chunks
    __bf16* W1p  = W0p + (size_t)320 * 13312;
    __bf16* W2p  = W1p + CH;
    __bf16* Wh0p = W2p + CH;
    __bf16* Wh1p = Wh0p + CH;
    __bf16* Wh2p = Wh1p + CH;
    // total ws: ~40 MB

    // ---- prologue: pack all weights (one launch) ----
    pack_all<<<1024, 256, 0, stream>>>(W_ih0, W_ih1, W_ih2,
                                       W_hh0, W_hh1, W_hh2,
                                       W0p, W1p, W2p, Wh0p, Wh1p, Wh2p);

    // ---- layer 0: K=10000, 16-way k-split (20 ksteps each), partials ----
    gemm_pipe<<<dim3(32, 16), 512, 0, stream>>>(x, 10000, 10000, W0p, Ppart, (int)PE, 20);
    reduce_parts<<<400, 256, 0, stream>>>(Ppart, P);
    rnn_recM<<<32, 512, 0, stream>>>(P, Wh0p, b_ih0, b_hh0, Hbuf);

    // ---- layer 1: K=200, single split, direct store ----
    gemm_pipe<<<dim3(32, 1), 512, 0, stream>>>(Hbuf, HDIM, HDIM, W1p, P, (int)PE, 7);
    rnn_recM<<<32, 512, 0, stream>>>(P, Wh1p, b_ih1, b_hh1, Hbuf2);

    // ---- layer 2 ----
    gemm_pipe<<<dim3(32, 1), 512, 0, stream>>>(Hbuf2, HDIM, HDIM, W2p, P, (int)PE, 7);
    rnn_recM<<<32, 512, 0, stream>>>(P, Wh2p, b_ih2, b_hh2, Hbuf);

    // ---- FC head ----
    fc_head<<<1, 64, 0, stream>>>(Hbuf, fc_w, fc_b, out);
}